// Round 2
// baseline (196.702 us; speedup 1.0000x reference)
//
#include <hip/hip_runtime.h>

#define B_ 4
#define N_ 4096
#define C_ 256
#define M_ 2048

typedef __attribute__((ext_vector_type(8))) short short8;
typedef __attribute__((ext_vector_type(4))) float f32x4;

union U16x8 { uint4 u4; unsigned short us[8]; short8 s8; };

__device__ __forceinline__ float bf2f(unsigned short h) {
    unsigned int u = ((unsigned int)h) << 16;
    return __builtin_bit_cast(float, u);
}
__device__ __forceinline__ unsigned short f2bf(float f) {
    unsigned int u = __builtin_bit_cast(unsigned int, f);
    u += 0x7FFFu + ((u >> 16) & 1u);
    return (unsigned short)(u >> 16);
}

// ---------------- Prepass 1: inv g-norm per (b, m) (f32 input) ----------------
__global__ void k_gnorm(const float* __restrict__ g, float* __restrict__ invgn) {
    int idx = blockIdx.x * 256 + threadIdx.x;   // [0, B*M)
    int b = idx >> 11;                          // M = 2048
    int m = idx & (M_ - 1);
    const float* gb = g + (size_t)b * C_ * M_ + m;
    float s = 0.f;
#pragma unroll 4
    for (int c = 0; c < C_; ++c) {
        float v = gb[(size_t)c * M_];
        s += v * v;
    }
    invgn[idx] = 1.0f / fmaxf(sqrtf(s), 1e-8f);
}

// ---- Prepass 2: gcm = bf16(g) [b][c][m];  gmc = bf16(g * invgn) transposed [b][m][c] ----
__global__ void k_prep(const float* __restrict__ g,
                       const float* __restrict__ invgn,
                       unsigned short* __restrict__ gcm,
                       unsigned short* __restrict__ gmc) {
    __shared__ unsigned short T[64 * 66];   // stride 66: /4 odd -> conflict-free transpose
    __shared__ float sc[64];
    int b = blockIdx.z, c0 = blockIdx.y * 64, m0 = blockIdx.x * 64;
    int tid = threadIdx.x;
    if (tid < 64) sc[tid] = invgn[b * M_ + m0 + tid];
    __syncthreads();
    const float* src = g + ((size_t)b * C_ + c0) * M_ + m0;
    unsigned short* rawdst = gcm + ((size_t)b * C_ + c0) * M_ + m0;
#pragma unroll
    for (int i = 0; i < 16; ++i) {
        int id = tid + 256 * i;
        int ci = id >> 6, mj = id & 63;
        float v = src[(size_t)ci * M_ + mj];
        rawdst[(size_t)ci * M_ + mj] = f2bf(v);
        T[ci * 66 + mj] = f2bf(v * sc[mj]);
    }
    __syncthreads();
    unsigned short* dst = gmc + ((size_t)b * M_ + m0) * C_ + c0;
#pragma unroll
    for (int i = 0; i < 16; ++i) {
        int id = tid + 256 * i;
        int mj = id >> 6, ci = id & 63;
        dst[(size_t)mj * C_ + ci] = T[ci * 66 + mj];
    }
}

// ---------------- Main fused kernel ----------------
// Block: 256 thr (4 waves), 64 query rows of one batch. Wave w owns rows w*16..w*16+15.
// M-loop over 64-key tiles: S = Qhat*Ghat^T (MFMA) -> p = exp2(S*2.5*log2e) ->
// P to LDS (wave-private rows) -> O += P * Graw^T (MFMA). Divide by row-sum at end.
__global__ __launch_bounds__(256, 2) void k_main(
    const float* __restrict__ l,
    const unsigned short* __restrict__ gcm,    // [B][C][M] raw bf16 (GEMM2 B, k=m contiguous)
    const unsigned short* __restrict__ gmc,    // [B][M][C] normalized bf16 (GEMM1 B, k=c contiguous)
    float* __restrict__ out)
{
    // pads: row stride (dwords) % 32 == 4 -> 2-way bank alias (free), 16B aligned
    __shared__ __align__(16) unsigned short sGmc[64 * 264];   // ghat tile [m][c]   33792 B
    __shared__ __align__(16) unsigned short sGcm[256 * 72];   // raw g tile [c][m]  36864 B
    __shared__ __align__(16) unsigned short sP[64 * 72];      // P tile [n][m]       9216 B

    const int tid = threadIdx.x;
    const int w = tid >> 6;
    const int lane = tid & 63;
    const int l15 = lane & 15;
    const int quad = lane >> 4;
    const int b = blockIdx.y;
    const int row0 = blockIdx.x * 64;

    // ---- Q: load my A-frag rows (f32), row norm, normalize -> bf16 register frags ----
    const float* lrow = l + ((size_t)b * N_ + row0 + w * 16 + l15) * C_;
    U16x8 qtmp[8];
    float ss = 0.f;
#pragma unroll
    for (int kk = 0; kk < 8; ++kk) {
        float4 x0 = *(const float4*)(lrow + kk * 32 + quad * 8);
        float4 x1 = *(const float4*)(lrow + kk * 32 + quad * 8 + 4);
        ss += x0.x*x0.x + x0.y*x0.y + x0.z*x0.z + x0.w*x0.w;
        ss += x1.x*x1.x + x1.y*x1.y + x1.z*x1.z + x1.w*x1.w;
        qtmp[kk].us[0] = f2bf(x0.x); qtmp[kk].us[1] = f2bf(x0.y);
        qtmp[kk].us[2] = f2bf(x0.z); qtmp[kk].us[3] = f2bf(x0.w);
        qtmp[kk].us[4] = f2bf(x1.x); qtmp[kk].us[5] = f2bf(x1.y);
        qtmp[kk].us[6] = f2bf(x1.z); qtmp[kk].us[7] = f2bf(x1.w);
    }
    ss += __shfl_xor(ss, 16);   // reduce across the 4 quads holding the same row
    ss += __shfl_xor(ss, 32);
    const float invl = 1.0f / fmaxf(sqrtf(ss), 1e-8f);
    short8 qf[8];
#pragma unroll
    for (int kk = 0; kk < 8; ++kk) {
        U16x8 t;
#pragma unroll
        for (int j = 0; j < 8; ++j) t.us[j] = f2bf(bf2f(qtmp[kk].us[j]) * invl);
        qf[kk] = t.s8;
    }

    f32x4 zero = {0.f, 0.f, 0.f, 0.f};
    f32x4 o[16];
#pragma unroll
    for (int i = 0; i < 16; ++i) o[i] = zero;
    float dl[4] = {0.f, 0.f, 0.f, 0.f};

    const unsigned short* gmc_b = gmc + (size_t)b * M_ * C_;
    const unsigned short* gcm_b = gcm + (size_t)b * C_ * M_;

    for (int mt = 0; mt < M_ / 64; ++mt) {
        const int m0 = mt * 64;
        // stage ghat [m][c]: 64 rows x 512 B
#pragma unroll
        for (int i = 0; i < 8; ++i) {
            int id = tid + 256 * i;
            int r = id >> 5, c16 = id & 31;
            *(uint4*)&sGmc[r * 264 + c16 * 8] =
                *(const uint4*)(gmc_b + (size_t)(m0 + r) * C_ + c16 * 8);
        }
        // stage raw g [c][m]: 256 rows x 128 B
#pragma unroll
        for (int i = 0; i < 8; ++i) {
            int id = tid + 256 * i;
            int c = id >> 3, c16 = id & 7;
            *(uint4*)&sGcm[c * 72 + c16 * 8] =
                *(const uint4*)(gcm_b + (size_t)c * M_ + m0 + c16 * 8);
        }
        __syncthreads();

        // GEMM1: S(16 rows x 64 cols) over K=256
        f32x4 s0 = zero, s1 = zero, s2 = zero, s3 = zero;
#pragma unroll
        for (int kk = 0; kk < 8; ++kk) {
            const int off = kk * 32 + quad * 8;
            short8 a = qf[kk];
            short8 b0 = *(const short8*)&sGmc[(l15     ) * 264 + off];
            short8 b1 = *(const short8*)&sGmc[(l15 + 16) * 264 + off];
            short8 b2 = *(const short8*)&sGmc[(l15 + 32) * 264 + off];
            short8 b3 = *(const short8*)&sGmc[(l15 + 48) * 264 + off];
            s0 = __builtin_amdgcn_mfma_f32_16x16x32_bf16(a, b0, s0, 0, 0, 0);
            s1 = __builtin_amdgcn_mfma_f32_16x16x32_bf16(a, b1, s1, 0, 0, 0);
            s2 = __builtin_amdgcn_mfma_f32_16x16x32_bf16(a, b2, s2, 0, 0, 0);
            s3 = __builtin_amdgcn_mfma_f32_16x16x32_bf16(a, b3, s3, 0, 0, 0);
        }

        // p = exp(cos/tau); accumulate row denominators; write P (wave-private rows)
        const int prow = (w * 16 + quad * 4) * 72;
#pragma unroll
        for (int ct = 0; ct < 4; ++ct) {
            f32x4 sv = (ct == 0) ? s0 : (ct == 1) ? s1 : (ct == 2) ? s2 : s3;
#pragma unroll
            for (int r = 0; r < 4; ++r) {
                float p = exp2f(sv[r] * 3.6067376022224085f);  // (1/0.4)*log2(e)
                dl[r] += p;
                sP[prow + r * 72 + ct * 16 + l15] = f2bf(p);
            }
        }
        // no barrier: each wave reads only its own P rows (DS ops in-order per wave)

        // GEMM2: O(16 x 256) += P(16 x 64) * V(64 x 256), V[m][c] = graw[c][m]
#pragma unroll
        for (int k2 = 0; k2 < 2; ++k2) {
            short8 a2 = *(const short8*)&sP[(w * 16 + l15) * 72 + k2 * 32 + quad * 8];
#pragma unroll
            for (int nt = 0; nt < 16; ++nt) {
                short8 b2 = *(const short8*)&sGcm[(nt * 16 + l15) * 72 + k2 * 32 + quad * 8];
                o[nt] = __builtin_amdgcn_mfma_f32_16x16x32_bf16(a2, b2, o[nt], 0, 0, 0);
            }
        }
        __syncthreads();   // protect sGmc/sGcm before next stage
    }

    // ---- row denominators: reduce across the 16 lanes of each quad ----
#pragma unroll
    for (int r = 0; r < 4; ++r) {
        float d = dl[r];
        d += __shfl_xor(d, 1);
        d += __shfl_xor(d, 2);
        d += __shfl_xor(d, 4);
        d += __shfl_xor(d, 8);
        dl[r] = 1.0f / d;
    }

    // ---- epilogue: out = l + O/denom (C-layout: row = quad*4+r, col = nt*16+l15) ----
    const size_t obase = ((size_t)b * N_ + row0 + w * 16 + quad * 4) * C_;
#pragma unroll
    for (int nt = 0; nt < 16; ++nt) {
        int c = nt * 16 + l15;
#pragma unroll
        for (int r = 0; r < 4; ++r) {
            out[obase + (size_t)r * C_ + c] = l[obase + (size_t)r * C_ + c] + o[nt][r] * dl[r];
        }
    }
}

extern "C" void kernel_launch(void* const* d_in, const int* in_sizes, int n_in,
                              void* d_out, int out_size, void* d_ws, size_t ws_size,
                              hipStream_t stream) {
    (void)in_sizes; (void)n_in; (void)out_size; (void)ws_size;
    const float* l = (const float*)d_in[0];
    const float* g = (const float*)d_in[1];
    float* outp = (float*)d_out;

    char* ws = (char*)d_ws;
    float* invgn = (float*)ws;                                  // 32 KB
    unsigned short* gmc = (unsigned short*)(ws + 32768);        // 4 MB  (normalized, [b][m][c])
    unsigned short* gcm = (unsigned short*)(ws + 32768 + (size_t)B_ * M_ * C_ * 2); // 4 MB (raw, [b][c][m])

    k_gnorm<<<dim3((B_ * M_) / 256), 256, 0, stream>>>(g, invgn);
    k_prep<<<dim3(M_ / 64, C_ / 64, B_), 256, 0, stream>>>(g, invgn, gcm, gmc);
    k_main<<<dim3(N_ / 64, B_), 256, 0, stream>>>(l, gcm, gmc, outp);
}